// Round 10
// baseline (2954.496 us; speedup 1.0000x reference)
//
#include <hip/hip_runtime.h>

// ---------------------------------------------------------------------------
// DGCN layer on MI355X — round 4 (resubmit #2): register-blocked dense kernels.
// Round-3 postmortem: final_mm 104us vs 21us VALU floor (VALUBusy 45%,
// 2 LDS reads per 4 FMA). Fix: 4x4 register tile per thread
// (1 Ws float4 + 4 Xs scalars -> 16 FMA per k). mm64 same treatment.
// All non-dense kernels byte-identical to the measured round-3 version.
// ---------------------------------------------------------------------------

// ---------- dense [N,64] @ [64,64], 64 rows/block, thread = 4 rows x 4 cols ----------
__global__ __launch_bounds__(256) void mm64(const float* __restrict__ X,
                                            const float* __restrict__ W,
                                            float* __restrict__ Y, int N) {
  __shared__ float Ws[64 * 64];   // 16 KB
  __shared__ float Xs[64 * 68];   // 17.4 KB (pad 68)
  const int t = threadIdx.x;
  for (int i = t * 4; i < 64 * 64; i += 1024)
    *(float4*)&Ws[i] = *(const float4*)&W[i];
  const int c4 = (t & 15) * 4;
  const int rq = t >> 4;                 // 0..15
  const int row0 = blockIdx.x * 64;
  for (int rb = 0; rb < 64; rb += 16) {
    const int r = row0 + rb + rq;
    if (r < N)
      *(float4*)&Xs[(rb + rq) * 68 + c4] = *(const float4*)&X[(size_t)r * 64 + c4];
  }
  __syncthreads();
  float4 a0 = {0.f, 0.f, 0.f, 0.f}, a1 = a0, a2 = a0, a3 = a0;
  const int xr = rq * 4;
#pragma unroll
  for (int k = 0; k < 64; ++k) {
    const float4 wv = *(const float4*)&Ws[k * 64 + c4];
    const float x0 = Xs[(xr + 0) * 68 + k];
    const float x1 = Xs[(xr + 1) * 68 + k];
    const float x2 = Xs[(xr + 2) * 68 + k];
    const float x3 = Xs[(xr + 3) * 68 + k];
    a0.x += x0 * wv.x; a0.y += x0 * wv.y; a0.z += x0 * wv.z; a0.w += x0 * wv.w;
    a1.x += x1 * wv.x; a1.y += x1 * wv.y; a1.z += x1 * wv.z; a1.w += x1 * wv.w;
    a2.x += x2 * wv.x; a2.y += x2 * wv.y; a2.z += x2 * wv.z; a2.w += x2 * wv.w;
    a3.x += x3 * wv.x; a3.y += x3 * wv.y; a3.z += x3 * wv.z; a3.w += x3 * wv.w;
  }
  const int r = row0 + xr;
  if (r + 0 < N) *(float4*)&Y[(size_t)(r + 0) * 64 + c4] = a0;
  if (r + 1 < N) *(float4*)&Y[(size_t)(r + 1) * 64 + c4] = a1;
  if (r + 2 < N) *(float4*)&Y[(size_t)(r + 2) * 64 + c4] = a2;
  if (r + 3 < N) *(float4*)&Y[(size_t)(r + 3) * 64 + c4] = a3;
}

// ---------- final: relu(concat(HO,FEA)[N,128] @ W[128,64] + b), 4x4 tile ----------
__global__ __launch_bounds__(256) void final_mm(const float* __restrict__ HO,
                                                const float* __restrict__ FEA,
                                                const float* __restrict__ W,
                                                const float* __restrict__ b,
                                                float* __restrict__ Y, int N) {
  __shared__ float Ws[128 * 64];  // 32 KB
  __shared__ float Xs[64 * 68];   // 17.4 KB, reused HO then FEA
  const int t = threadIdx.x;
  for (int i = t * 4; i < 128 * 64; i += 1024)
    *(float4*)&Ws[i] = *(const float4*)&W[i];
  const int c4 = (t & 15) * 4;
  const int rq = t >> 4;
  const int row0 = blockIdx.x * 64;
  // chunk 1: HO
  for (int rb = 0; rb < 64; rb += 16) {
    const int r = row0 + rb + rq;
    if (r < N)
      *(float4*)&Xs[(rb + rq) * 68 + c4] = *(const float4*)&HO[(size_t)r * 64 + c4];
  }
  __syncthreads();
  float4 a0 = {0.f, 0.f, 0.f, 0.f}, a1 = a0, a2 = a0, a3 = a0;
  const int xr = rq * 4;
#pragma unroll
  for (int k = 0; k < 64; ++k) {
    const float4 wv = *(const float4*)&Ws[k * 64 + c4];
    const float x0 = Xs[(xr + 0) * 68 + k];
    const float x1 = Xs[(xr + 1) * 68 + k];
    const float x2 = Xs[(xr + 2) * 68 + k];
    const float x3 = Xs[(xr + 3) * 68 + k];
    a0.x += x0 * wv.x; a0.y += x0 * wv.y; a0.z += x0 * wv.z; a0.w += x0 * wv.w;
    a1.x += x1 * wv.x; a1.y += x1 * wv.y; a1.z += x1 * wv.z; a1.w += x1 * wv.w;
    a2.x += x2 * wv.x; a2.y += x2 * wv.y; a2.z += x2 * wv.z; a2.w += x2 * wv.w;
    a3.x += x3 * wv.x; a3.y += x3 * wv.y; a3.z += x3 * wv.z; a3.w += x3 * wv.w;
  }
  // chunk 2: FEA (k = 64..127)
  __syncthreads();
  for (int rb = 0; rb < 64; rb += 16) {
    const int r = row0 + rb + rq;
    if (r < N)
      *(float4*)&Xs[(rb + rq) * 68 + c4] = *(const float4*)&FEA[(size_t)r * 64 + c4];
  }
  __syncthreads();
#pragma unroll
  for (int k = 0; k < 64; ++k) {
    const float4 wv = *(const float4*)&Ws[(64 + k) * 64 + c4];
    const float x0 = Xs[(xr + 0) * 68 + k];
    const float x1 = Xs[(xr + 1) * 68 + k];
    const float x2 = Xs[(xr + 2) * 68 + k];
    const float x3 = Xs[(xr + 3) * 68 + k];
    a0.x += x0 * wv.x; a0.y += x0 * wv.y; a0.z += x0 * wv.z; a0.w += x0 * wv.w;
    a1.x += x1 * wv.x; a1.y += x1 * wv.y; a1.z += x1 * wv.z; a1.w += x1 * wv.w;
    a2.x += x2 * wv.x; a2.y += x2 * wv.y; a2.z += x2 * wv.z; a2.w += x2 * wv.w;
    a3.x += x3 * wv.x; a3.y += x3 * wv.y; a3.z += x3 * wv.z; a3.w += x3 * wv.w;
  }
  const float4 bv = *(const float4*)&b[c4];
  const int r = row0 + xr;
  if (r + 0 < N) {
    float4 v = a0;
    v.x = fmaxf(v.x + bv.x, 0.f); v.y = fmaxf(v.y + bv.y, 0.f);
    v.z = fmaxf(v.z + bv.z, 0.f); v.w = fmaxf(v.w + bv.w, 0.f);
    *(float4*)&Y[(size_t)(r + 0) * 64 + c4] = v;
  }
  if (r + 1 < N) {
    float4 v = a1;
    v.x = fmaxf(v.x + bv.x, 0.f); v.y = fmaxf(v.y + bv.y, 0.f);
    v.z = fmaxf(v.z + bv.z, 0.f); v.w = fmaxf(v.w + bv.w, 0.f);
    *(float4*)&Y[(size_t)(r + 1) * 64 + c4] = v;
  }
  if (r + 2 < N) {
    float4 v = a2;
    v.x = fmaxf(v.x + bv.x, 0.f); v.y = fmaxf(v.y + bv.y, 0.f);
    v.z = fmaxf(v.z + bv.z, 0.f); v.w = fmaxf(v.w + bv.w, 0.f);
    *(float4*)&Y[(size_t)(r + 2) * 64 + c4] = v;
  }
  if (r + 3 < N) {
    float4 v = a3;
    v.x = fmaxf(v.x + bv.x, 0.f); v.y = fmaxf(v.y + bv.y, 0.f);
    v.z = fmaxf(v.z + bv.z, 0.f); v.w = fmaxf(v.w + bv.w, 0.f);
    *(float4*)&Y[(size_t)(r + 3) * 64 + c4] = v;
  }
}

// ---------- cvec[which*64+k] = dot(Wg[k][:], a_half) ----------
__global__ void make_cvecs(const float* __restrict__ W3, const float* __restrict__ a3,
                           const float* __restrict__ W4, const float* __restrict__ a4,
                           float* __restrict__ cv) {
  const int t = threadIdx.x;          // 256
  const int k = t & 63;
  const int which = t >> 6;
  const float* W = (which < 2) ? W3 : W4;
  const float* a = ((which < 2) ? a3 : a4) + (which & 1) * 64;
  float acc = 0.f;
#pragma unroll
  for (int c = 0; c < 64; ++c) acc += W[k * 64 + c] * a[c];
  cv[which * 64 + k] = acc;
}

// ---------- s[row] = dot(X[row], c) ----------
__global__ __launch_bounds__(256) void matvec64(const float* __restrict__ X,
                                                const float* __restrict__ c,
                                                float* __restrict__ s, int N) {
  const int g = blockIdx.x * 256 + threadIdx.x;
  const int row = g >> 4, lane = g & 15;
  if (row >= N) return;
  const float4 x = *(const float4*)&X[(size_t)row * 64 + lane * 4];
  const float4 cv = *(const float4*)&c[lane * 4];
  float v = x.x * cv.x + x.y * cv.y + x.z * cv.z + x.w * cv.w;
  v += __shfl_xor(v, 1, 16);
  v += __shfl_xor(v, 2, 16);
  v += __shfl_xor(v, 4, 16);
  v += __shfl_xor(v, 8, 16);
  if (lane == 0) s[row] = v;
}

// ---------- CSR build: histogram ----------
__global__ __launch_bounds__(256) void hist_kernel(const int* __restrict__ dst,
                                                   int* __restrict__ cnt, int E) {
  int i = blockIdx.x * 256 + threadIdx.x;
  const int stride = gridDim.x * 256;
  for (; i < E; i += stride) atomicAdd(&cnt[dst[i]], 1);
}

// ---------- scan step 1: per-block sums (1024 elems / 256-thr block) ----------
__global__ __launch_bounds__(256) void scan_partial(const int* __restrict__ cnt, int N,
                                                    int* __restrict__ bs) {
  __shared__ int red[256];
  const int t = threadIdx.x;
  const int base = blockIdx.x * 1024 + t * 4;
  int s = 0;
  if (base + 3 < N) {
    const int4 v = *(const int4*)&cnt[base];
    s = v.x + v.y + v.z + v.w;
  } else {
#pragma unroll
    for (int j = 0; j < 4; ++j) if (base + j < N) s += cnt[base + j];
  }
  red[t] = s;
  __syncthreads();
  for (int off = 128; off > 0; off >>= 1) {
    if (t < off) red[t] += red[t + off];
    __syncthreads();
  }
  if (t == 0) bs[blockIdx.x] = red[0];
}

// ---------- scan step 2: exclusive scan of block sums (nb <= 1024) ----------
__global__ __launch_bounds__(1024) void scan_sums(int* __restrict__ bs, int nb) {
  __shared__ int sm[1024];
  const int t = threadIdx.x;
  const int v = (t < nb) ? bs[t] : 0;
  sm[t] = v;
  __syncthreads();
  for (int off = 1; off < 1024; off <<= 1) {
    const int o = (t >= off) ? sm[t - off] : 0;
    __syncthreads();
    sm[t] += o;
    __syncthreads();
  }
  if (t < nb) bs[t] = sm[t] - v;  // exclusive
}

// ---------- scan step 3: rescan with block offset, write rp + cur ----------
__global__ __launch_bounds__(256) void scan_blocks(const int* __restrict__ cnt, int N, int E,
                                                   const int* __restrict__ bs,
                                                   int* __restrict__ rp, int* __restrict__ cur) {
  __shared__ int tsum[256];
  const int t = threadIdx.x;
  const int base = blockIdx.x * 1024 + t * 4;
  int v0 = 0, v1 = 0, v2 = 0, v3 = 0;
  if (base + 3 < N) {
    const int4 v = *(const int4*)&cnt[base];
    v0 = v.x; v1 = v.y; v2 = v.z; v3 = v.w;
  } else {
    if (base + 0 < N) v0 = cnt[base + 0];
    if (base + 1 < N) v1 = cnt[base + 1];
    if (base + 2 < N) v2 = cnt[base + 2];
    if (base + 3 < N) v3 = cnt[base + 3];
  }
  const int s = v0 + v1 + v2 + v3;
  tsum[t] = s;
  __syncthreads();
  for (int off = 1; off < 256; off <<= 1) {
    const int o = (t >= off) ? tsum[t - off] : 0;
    __syncthreads();
    tsum[t] += o;
    __syncthreads();
  }
  int p = bs[blockIdx.x] + tsum[t] - s;  // exclusive prefix at base
  if (base + 0 < N) { rp[base + 0] = p; cur[base + 0] = p; p += v0; }
  if (base + 1 < N) { rp[base + 1] = p; cur[base + 1] = p; p += v1; }
  if (base + 2 < N) { rp[base + 2] = p; cur[base + 2] = p; p += v2; }
  if (base + 3 < N) { rp[base + 3] = p; cur[base + 3] = p; p += v3; }
  if (blockIdx.x == 0 && t == 0) rp[N] = E;
}

// ---------- CSR build: reorder payload by dst ----------
__global__ __launch_bounds__(256) void reorder_kernel(const int* __restrict__ dst,
                                                      const int* __restrict__ src,
                                                      const float* __restrict__ w,
                                                      int* __restrict__ cur,
                                                      int* __restrict__ srcs,
                                                      float* __restrict__ ws, int E) {
  int i = blockIdx.x * 256 + threadIdx.x;
  const int stride = gridDim.x * 256;
  for (; i < E; i += stride) {
    const int d = dst[i];
    const int p = atomicAdd(&cur[d], 1);
    srcs[p] = src[i];
    ws[p] = w[i];
  }
}

// ---------- GCN: out[row] = b + sum_{e in row} w[e] * sup[srcs[e]] ----------
__global__ __launch_bounds__(256) void gcn_gather(const int* __restrict__ rp,
                                                  const int* __restrict__ srcs,
                                                  const float* __restrict__ w,
                                                  const float* __restrict__ sup,
                                                  const float* __restrict__ b,
                                                  float* __restrict__ out, int N) {
  const int wid = (blockIdx.x * 256 + threadIdx.x) >> 6;
  const int lane = threadIdx.x & 63;
  if (wid >= N) return;
  const int beg = rp[wid], end = rp[wid + 1];
  const int slot = lane >> 4, c4 = (lane & 15) * 4;
  float4 acc = {0.f, 0.f, 0.f, 0.f};
  for (int j = beg + slot; j < end; j += 4) {
    const int s = srcs[j];
    const float wv = w[j];
    const float4 v = *(const float4*)&sup[(size_t)s * 64 + c4];
    acc.x += wv * v.x; acc.y += wv * v.y; acc.z += wv * v.z; acc.w += wv * v.w;
  }
#pragma unroll
  for (int m = 16; m <= 32; m <<= 1) {
    acc.x += __shfl_xor(acc.x, m);
    acc.y += __shfl_xor(acc.y, m);
    acc.z += __shfl_xor(acc.z, m);
    acc.w += __shfl_xor(acc.w, m);
  }
  if (lane < 16) {
    const float4 bv = *(const float4*)&b[c4];
    acc.x += bv.x; acc.y += bv.y; acc.z += bv.z; acc.w += bv.w;
    *(float4*)&out[(size_t)wid * 64 + c4] = acc;
  }
}

// ---------- fused GAT: per dst row: max pass, then exp+den+weighted gather ----------
__global__ __launch_bounds__(256) void gat_fused(const int* __restrict__ rp,
                                                 const int* __restrict__ srcs,
                                                 const float* __restrict__ sdst,
                                                 const float* __restrict__ ssrc,
                                                 const float* __restrict__ hs,
                                                 float* __restrict__ out, int N) {
  const int wid = (blockIdx.x * 256 + threadIdx.x) >> 6;
  const int lane = threadIdx.x & 63;
  if (wid >= N) return;
  const int beg = rp[wid], end = rp[wid + 1];
  const int deg = end - beg;
  const float sd = sdst[wid];
  float m = -3.4e38f;
  for (int k = lane; k < deg; k += 64) {
    float v = sd + ssrc[srcs[beg + k]];
    v = (v >= 0.f) ? v : 0.2f * v;
    m = fmaxf(m, v);
  }
#pragma unroll
  for (int off = 1; off < 64; off <<= 1) m = fmaxf(m, __shfl_xor(m, off));
  const int slot = lane >> 4, c4 = (lane & 15) * 4;
  float4 acc = {0.f, 0.f, 0.f, 0.f};
  float den = 0.f;
  for (int j = beg + slot; j < end; j += 4) {
    const int s = srcs[j];
    float v = sd + ssrc[s];
    v = (v >= 0.f) ? v : 0.2f * v;
    const float ex = expf(v - m);
    const float4 hv = *(const float4*)&hs[(size_t)s * 64 + c4];
    acc.x += ex * hv.x; acc.y += ex * hv.y; acc.z += ex * hv.z; acc.w += ex * hv.w;
    den += ex;  // same value across the 16 lanes of this slot
  }
#pragma unroll
  for (int mm = 16; mm <= 32; mm <<= 1) {
    acc.x += __shfl_xor(acc.x, mm);
    acc.y += __shfl_xor(acc.y, mm);
    acc.z += __shfl_xor(acc.z, mm);
    acc.w += __shfl_xor(acc.w, mm);
    den   += __shfl_xor(den, mm);
  }
  if (lane < 16) {
    const float inv = 1.f / (den + 1e-16f);
    acc.x *= inv; acc.y *= inv; acc.z *= inv; acc.w *= inv;
    *(float4*)&out[(size_t)wid * 64 + c4] = acc;
  }
}

extern "C" void kernel_launch(void* const* d_in, const int* in_sizes, int n_in,
                              void* d_out, int out_size, void* d_ws, size_t ws_size,
                              hipStream_t stream) {
  const float* ufea   = (const float*)d_in[0];
  const float* vfea   = (const float*)d_in[1];
  const int*   edge_user = (const int*)d_in[2];
  const int*   edge_item = (const int*)d_in[3];
  const float* uv_w   = (const float*)d_in[4];
  const float* vu_w   = (const float*)d_in[5];
  const float* W_gc1  = (const float*)d_in[6];
  const float* b_gc1  = (const float*)d_in[7];
  const float* W_gc2  = (const float*)d_in[8];
  const float* b_gc2  = (const float*)d_in[9];
  const float* W_gat3 = (const float*)d_in[10];
  const float* a_gat3 = (const float*)d_in[11];
  const float* W_gat4 = (const float*)d_in[12];
  const float* a_gat4 = (const float*)d_in[13];
  const float* W_user = (const float*)d_in[14];
  const float* b_user = (const float*)d_in[15];
  const float* W_item = (const float*)d_in[16];
  const float* b_item = (const float*)d_in[17];

  const int NU = in_sizes[0] / 64;
  const int NI = in_sizes[1] / 64;
  const int E  = in_sizes[2];

  float* ws = (float*)d_ws;
  size_t o = 0;
  auto pad4 = [](size_t x) { return (x + 3) & ~(size_t)3; };  // keep 16B alignment
  float* P0 = ws + o; o += (size_t)NU * 64;   // support1 -> hs4
  float* P1 = ws + o; o += (size_t)NI * 64;   // support2 -> hs3
  float* P2 = ws + o; o += (size_t)NI * 64;   // user_ho_i -> item_ho
  float* P3 = ws + o; o += (size_t)NU * 64;   // item_ho_u -> user_ho
  float* s_dst3 = ws + o; o += NU;
  float* s_src3 = ws + o; o += NI;
  float* s_dst4 = ws + o; o += NI;
  float* s_src4 = ws + o; o += NU;
  float* cvec = ws + o; o += 256;
  // CSR by item (dst = edge_item)
  int* cntI = (int*)(ws + o); o += NI;
  int* rpI  = (int*)(ws + o); o += pad4(NI + 1);
  int* curI = (int*)(ws + o); o += NI;
  int* srcU_byI = (int*)(ws + o); o += E;
  float* wVU_byI = ws + o; o += E;
  // CSR by user (dst = edge_user)
  int* cntU = (int*)(ws + o); o += NU;
  int* rpU  = (int*)(ws + o); o += pad4(NU + 1);
  int* curU = (int*)(ws + o); o += NU;
  int* srcI_byU = (int*)(ws + o); o += E;
  float* wUV_byU = ws + o; o += E;
  // scan block sums
  int* bsI = (int*)(ws + o); o += 1024;
  int* bsU = (int*)(ws + o); o += 1024;

  float* out_user = (float*)d_out;
  float* out_item = out_user + (size_t)NU * 64;

  const dim3 blk(256);
  const int gU = (NU + 63) / 64, gI = (NI + 63) / 64;   // 64-row dense blocks
  const int gE = (E + 255) / 256;
  const int gEs = min(gE, 2048);            // grid-stride kernels
  const int gwU = (NU + 3) / 4, gwI = (NI + 3) / 4;  // wave-per-row kernels
  const int gvU = (int)(((long)NU * 16 + 255) / 256);
  const int gvI = (int)(((long)NI * 16 + 255) / 256);
  const int nbI = (NI + 1023) / 1024, nbU = (NU + 1023) / 1024;  // scan blocks

  // ---- CSR build (both directions) ----
  hipMemsetAsync(cntI, 0, (size_t)NI * 4, stream);
  hipMemsetAsync(cntU, 0, (size_t)NU * 4, stream);
  hist_kernel<<<gEs, blk, 0, stream>>>(edge_item, cntI, E);
  hist_kernel<<<gEs, blk, 0, stream>>>(edge_user, cntU, E);
  scan_partial<<<nbI, blk, 0, stream>>>(cntI, NI, bsI);
  scan_sums<<<1, 1024, 0, stream>>>(bsI, nbI);
  scan_blocks<<<nbI, blk, 0, stream>>>(cntI, NI, E, bsI, rpI, curI);
  scan_partial<<<nbU, blk, 0, stream>>>(cntU, NU, bsU);
  scan_sums<<<1, 1024, 0, stream>>>(bsU, nbU);
  scan_blocks<<<nbU, blk, 0, stream>>>(cntU, NU, E, bsU, rpU, curU);
  reorder_kernel<<<gEs, blk, 0, stream>>>(edge_item, edge_user, vu_w, curI, srcU_byI, wVU_byI, E);
  reorder_kernel<<<gEs, blk, 0, stream>>>(edge_user, edge_item, uv_w, curU, srcI_byU, wUV_byU, E);

  // ---- GCN supports ----
  mm64<<<gU, blk, 0, stream>>>(ufea, W_gc1, P0, NU);
  mm64<<<gI, blk, 0, stream>>>(vfea, W_gc2, P1, NI);

  // ---- GCN gather-accumulate (atomic-free) ----
  gcn_gather<<<gwI, blk, 0, stream>>>(rpI, srcU_byI, wVU_byI, P0, b_gc1, P2, NI);  // user_ho_i
  gcn_gather<<<gwU, blk, 0, stream>>>(rpU, srcI_byU, wUV_byU, P1, b_gc2, P3, NU);  // item_ho_u

  // ---- GAT attention scalar projections: s = x @ (W @ a_half) ----
  make_cvecs<<<1, 256, 0, stream>>>(W_gat3, a_gat3, W_gat4, a_gat4, cvec);
  matvec64<<<gvU, blk, 0, stream>>>(ufea, cvec + 0,   s_dst3, NU);
  matvec64<<<gvI, blk, 0, stream>>>(P2,   cvec + 64,  s_src3, NI);
  matvec64<<<gvI, blk, 0, stream>>>(vfea, cvec + 128, s_dst4, NI);
  matvec64<<<gvU, blk, 0, stream>>>(P3,   cvec + 192, s_src4, NU);

  // ---- h_src for both GATs (reuse P1/P0) ----
  mm64<<<gI, blk, 0, stream>>>(P2, W_gat3, P1, NI);  // hs3
  mm64<<<gU, blk, 0, stream>>>(P3, W_gat4, P0, NU);  // hs4

  // ---- fused GAT (atomic-free, single pass kernel per direction) ----
  gat_fused<<<gwU, blk, 0, stream>>>(rpU, srcI_byU, s_dst3, s_src3, P1, P3, NU);  // user_ho
  gat_fused<<<gwI, blk, 0, stream>>>(rpI, srcU_byI, s_dst4, s_src4, P0, P2, NI);  // item_ho

  // ---- final linear + relu ----
  final_mm<<<gU, blk, 0, stream>>>(P3, ufea, W_user, b_user, out_user, NU);
  final_mm<<<gI, blk, 0, stream>>>(P2, vfea, W_item, b_item, out_item, NI);
}

// Round 11
// 917.651 us; speedup vs baseline: 3.2196x; 3.2196x over previous
//
#include <hip/hip_runtime.h>

// ---------------------------------------------------------------------------
// DGCN layer on MI355X — round 5: 4x4-tile dense kernels with BOUNDED unroll.
// Round-4 postmortem: full unroll of k=64 with 4x4 tile -> VGPR 256 + ~3.5GB
// scratch spill traffic per final_mm dispatch (1320us, 13x regression).
// Fix: #pragma unroll 4 bounds the live range (~80 VGPR expected, no spill).
// All non-dense kernels byte-identical to the measured round-3 version.
// ---------------------------------------------------------------------------

// ---------- dense [N,64] @ [64,64], 64 rows/block, thread = 4 rows x 4 cols ----------
__global__ __launch_bounds__(256) void mm64(const float* __restrict__ X,
                                            const float* __restrict__ W,
                                            float* __restrict__ Y, int N) {
  __shared__ float Ws[64 * 64];   // 16 KB
  __shared__ float Xs[64 * 68];   // 17.4 KB (pad 68)
  const int t = threadIdx.x;
  for (int i = t * 4; i < 64 * 64; i += 1024)
    *(float4*)&Ws[i] = *(const float4*)&W[i];
  const int c4 = (t & 15) * 4;
  const int rq = t >> 4;                 // 0..15
  const int row0 = blockIdx.x * 64;
  for (int rb = 0; rb < 64; rb += 16) {
    const int r = row0 + rb + rq;
    if (r < N)
      *(float4*)&Xs[(rb + rq) * 68 + c4] = *(const float4*)&X[(size_t)r * 64 + c4];
  }
  __syncthreads();
  float4 a0 = {0.f, 0.f, 0.f, 0.f}, a1 = a0, a2 = a0, a3 = a0;
  const int xr = rq * 4;
#pragma unroll 4
  for (int k = 0; k < 64; ++k) {
    const float4 wv = *(const float4*)&Ws[k * 64 + c4];
    const float x0 = Xs[(xr + 0) * 68 + k];
    const float x1 = Xs[(xr + 1) * 68 + k];
    const float x2 = Xs[(xr + 2) * 68 + k];
    const float x3 = Xs[(xr + 3) * 68 + k];
    a0.x += x0 * wv.x; a0.y += x0 * wv.y; a0.z += x0 * wv.z; a0.w += x0 * wv.w;
    a1.x += x1 * wv.x; a1.y += x1 * wv.y; a1.z += x1 * wv.z; a1.w += x1 * wv.w;
    a2.x += x2 * wv.x; a2.y += x2 * wv.y; a2.z += x2 * wv.z; a2.w += x2 * wv.w;
    a3.x += x3 * wv.x; a3.y += x3 * wv.y; a3.z += x3 * wv.z; a3.w += x3 * wv.w;
  }
  const int r = row0 + xr;
  if (r + 0 < N) *(float4*)&Y[(size_t)(r + 0) * 64 + c4] = a0;
  if (r + 1 < N) *(float4*)&Y[(size_t)(r + 1) * 64 + c4] = a1;
  if (r + 2 < N) *(float4*)&Y[(size_t)(r + 2) * 64 + c4] = a2;
  if (r + 3 < N) *(float4*)&Y[(size_t)(r + 3) * 64 + c4] = a3;
}

// ---------- final: relu(concat(HO,FEA)[N,128] @ W[128,64] + b), 4x4 tile ----------
__global__ __launch_bounds__(256) void final_mm(const float* __restrict__ HO,
                                                const float* __restrict__ FEA,
                                                const float* __restrict__ W,
                                                const float* __restrict__ b,
                                                float* __restrict__ Y, int N) {
  __shared__ float Ws[128 * 64];  // 32 KB
  __shared__ float Xs[64 * 68];   // 17.4 KB, reused HO then FEA
  const int t = threadIdx.x;
  for (int i = t * 4; i < 128 * 64; i += 1024)
    *(float4*)&Ws[i] = *(const float4*)&W[i];
  const int c4 = (t & 15) * 4;
  const int rq = t >> 4;
  const int row0 = blockIdx.x * 64;
  // chunk 1: HO
  for (int rb = 0; rb < 64; rb += 16) {
    const int r = row0 + rb + rq;
    if (r < N)
      *(float4*)&Xs[(rb + rq) * 68 + c4] = *(const float4*)&HO[(size_t)r * 64 + c4];
  }
  __syncthreads();
  float4 a0 = {0.f, 0.f, 0.f, 0.f}, a1 = a0, a2 = a0, a3 = a0;
  const int xr = rq * 4;
#pragma unroll 4
  for (int k = 0; k < 64; ++k) {
    const float4 wv = *(const float4*)&Ws[k * 64 + c4];
    const float x0 = Xs[(xr + 0) * 68 + k];
    const float x1 = Xs[(xr + 1) * 68 + k];
    const float x2 = Xs[(xr + 2) * 68 + k];
    const float x3 = Xs[(xr + 3) * 68 + k];
    a0.x += x0 * wv.x; a0.y += x0 * wv.y; a0.z += x0 * wv.z; a0.w += x0 * wv.w;
    a1.x += x1 * wv.x; a1.y += x1 * wv.y; a1.z += x1 * wv.z; a1.w += x1 * wv.w;
    a2.x += x2 * wv.x; a2.y += x2 * wv.y; a2.z += x2 * wv.z; a2.w += x2 * wv.w;
    a3.x += x3 * wv.x; a3.y += x3 * wv.y; a3.z += x3 * wv.z; a3.w += x3 * wv.w;
  }
  // chunk 2: FEA (k = 64..127)
  __syncthreads();
  for (int rb = 0; rb < 64; rb += 16) {
    const int r = row0 + rb + rq;
    if (r < N)
      *(float4*)&Xs[(rb + rq) * 68 + c4] = *(const float4*)&FEA[(size_t)r * 64 + c4];
  }
  __syncthreads();
#pragma unroll 4
  for (int k = 0; k < 64; ++k) {
    const float4 wv = *(const float4*)&Ws[(64 + k) * 64 + c4];
    const float x0 = Xs[(xr + 0) * 68 + k];
    const float x1 = Xs[(xr + 1) * 68 + k];
    const float x2 = Xs[(xr + 2) * 68 + k];
    const float x3 = Xs[(xr + 3) * 68 + k];
    a0.x += x0 * wv.x; a0.y += x0 * wv.y; a0.z += x0 * wv.z; a0.w += x0 * wv.w;
    a1.x += x1 * wv.x; a1.y += x1 * wv.y; a1.z += x1 * wv.z; a1.w += x1 * wv.w;
    a2.x += x2 * wv.x; a2.y += x2 * wv.y; a2.z += x2 * wv.z; a2.w += x2 * wv.w;
    a3.x += x3 * wv.x; a3.y += x3 * wv.y; a3.z += x3 * wv.z; a3.w += x3 * wv.w;
  }
  const float4 bv = *(const float4*)&b[c4];
  const int r = row0 + xr;
  if (r + 0 < N) {
    float4 v = a0;
    v.x = fmaxf(v.x + bv.x, 0.f); v.y = fmaxf(v.y + bv.y, 0.f);
    v.z = fmaxf(v.z + bv.z, 0.f); v.w = fmaxf(v.w + bv.w, 0.f);
    *(float4*)&Y[(size_t)(r + 0) * 64 + c4] = v;
  }
  if (r + 1 < N) {
    float4 v = a1;
    v.x = fmaxf(v.x + bv.x, 0.f); v.y = fmaxf(v.y + bv.y, 0.f);
    v.z = fmaxf(v.z + bv.z, 0.f); v.w = fmaxf(v.w + bv.w, 0.f);
    *(float4*)&Y[(size_t)(r + 1) * 64 + c4] = v;
  }
  if (r + 2 < N) {
    float4 v = a2;
    v.x = fmaxf(v.x + bv.x, 0.f); v.y = fmaxf(v.y + bv.y, 0.f);
    v.z = fmaxf(v.z + bv.z, 0.f); v.w = fmaxf(v.w + bv.w, 0.f);
    *(float4*)&Y[(size_t)(r + 2) * 64 + c4] = v;
  }
  if (r + 3 < N) {
    float4 v = a3;
    v.x = fmaxf(v.x + bv.x, 0.f); v.y = fmaxf(v.y + bv.y, 0.f);
    v.z = fmaxf(v.z + bv.z, 0.f); v.w = fmaxf(v.w + bv.w, 0.f);
    *(float4*)&Y[(size_t)(r + 3) * 64 + c4] = v;
  }
}

// ---------- cvec[which*64+k] = dot(Wg[k][:], a_half) ----------
__global__ void make_cvecs(const float* __restrict__ W3, const float* __restrict__ a3,
                           const float* __restrict__ W4, const float* __restrict__ a4,
                           float* __restrict__ cv) {
  const int t = threadIdx.x;          // 256
  const int k = t & 63;
  const int which = t >> 6;
  const float* W = (which < 2) ? W3 : W4;
  const float* a = ((which < 2) ? a3 : a4) + (which & 1) * 64;
  float acc = 0.f;
#pragma unroll
  for (int c = 0; c < 64; ++c) acc += W[k * 64 + c] * a[c];
  cv[which * 64 + k] = acc;
}

// ---------- s[row] = dot(X[row], c) ----------
__global__ __launch_bounds__(256) void matvec64(const float* __restrict__ X,
                                                const float* __restrict__ c,
                                                float* __restrict__ s, int N) {
  const int g = blockIdx.x * 256 + threadIdx.x;
  const int row = g >> 4, lane = g & 15;
  if (row >= N) return;
  const float4 x = *(const float4*)&X[(size_t)row * 64 + lane * 4];
  const float4 cv = *(const float4*)&c[lane * 4];
  float v = x.x * cv.x + x.y * cv.y + x.z * cv.z + x.w * cv.w;
  v += __shfl_xor(v, 1, 16);
  v += __shfl_xor(v, 2, 16);
  v += __shfl_xor(v, 4, 16);
  v += __shfl_xor(v, 8, 16);
  if (lane == 0) s[row] = v;
}

// ---------- CSR build: histogram ----------
__global__ __launch_bounds__(256) void hist_kernel(const int* __restrict__ dst,
                                                   int* __restrict__ cnt, int E) {
  int i = blockIdx.x * 256 + threadIdx.x;
  const int stride = gridDim.x * 256;
  for (; i < E; i += stride) atomicAdd(&cnt[dst[i]], 1);
}

// ---------- scan step 1: per-block sums (1024 elems / 256-thr block) ----------
__global__ __launch_bounds__(256) void scan_partial(const int* __restrict__ cnt, int N,
                                                    int* __restrict__ bs) {
  __shared__ int red[256];
  const int t = threadIdx.x;
  const int base = blockIdx.x * 1024 + t * 4;
  int s = 0;
  if (base + 3 < N) {
    const int4 v = *(const int4*)&cnt[base];
    s = v.x + v.y + v.z + v.w;
  } else {
#pragma unroll
    for (int j = 0; j < 4; ++j) if (base + j < N) s += cnt[base + j];
  }
  red[t] = s;
  __syncthreads();
  for (int off = 128; off > 0; off >>= 1) {
    if (t < off) red[t] += red[t + off];
    __syncthreads();
  }
  if (t == 0) bs[blockIdx.x] = red[0];
}

// ---------- scan step 2: exclusive scan of block sums (nb <= 1024) ----------
__global__ __launch_bounds__(1024) void scan_sums(int* __restrict__ bs, int nb) {
  __shared__ int sm[1024];
  const int t = threadIdx.x;
  const int v = (t < nb) ? bs[t] : 0;
  sm[t] = v;
  __syncthreads();
  for (int off = 1; off < 1024; off <<= 1) {
    const int o = (t >= off) ? sm[t - off] : 0;
    __syncthreads();
    sm[t] += o;
    __syncthreads();
  }
  if (t < nb) bs[t] = sm[t] - v;  // exclusive
}

// ---------- scan step 3: rescan with block offset, write rp + cur ----------
__global__ __launch_bounds__(256) void scan_blocks(const int* __restrict__ cnt, int N, int E,
                                                   const int* __restrict__ bs,
                                                   int* __restrict__ rp, int* __restrict__ cur) {
  __shared__ int tsum[256];
  const int t = threadIdx.x;
  const int base = blockIdx.x * 1024 + t * 4;
  int v0 = 0, v1 = 0, v2 = 0, v3 = 0;
  if (base + 3 < N) {
    const int4 v = *(const int4*)&cnt[base];
    v0 = v.x; v1 = v.y; v2 = v.z; v3 = v.w;
  } else {
    if (base + 0 < N) v0 = cnt[base + 0];
    if (base + 1 < N) v1 = cnt[base + 1];
    if (base + 2 < N) v2 = cnt[base + 2];
    if (base + 3 < N) v3 = cnt[base + 3];
  }
  const int s = v0 + v1 + v2 + v3;
  tsum[t] = s;
  __syncthreads();
  for (int off = 1; off < 256; off <<= 1) {
    const int o = (t >= off) ? tsum[t - off] : 0;
    __syncthreads();
    tsum[t] += o;
    __syncthreads();
  }
  int p = bs[blockIdx.x] + tsum[t] - s;  // exclusive prefix at base
  if (base + 0 < N) { rp[base + 0] = p; cur[base + 0] = p; p += v0; }
  if (base + 1 < N) { rp[base + 1] = p; cur[base + 1] = p; p += v1; }
  if (base + 2 < N) { rp[base + 2] = p; cur[base + 2] = p; p += v2; }
  if (base + 3 < N) { rp[base + 3] = p; cur[base + 3] = p; p += v3; }
  if (blockIdx.x == 0 && t == 0) rp[N] = E;
}

// ---------- CSR build: reorder payload by dst ----------
__global__ __launch_bounds__(256) void reorder_kernel(const int* __restrict__ dst,
                                                      const int* __restrict__ src,
                                                      const float* __restrict__ w,
                                                      int* __restrict__ cur,
                                                      int* __restrict__ srcs,
                                                      float* __restrict__ ws, int E) {
  int i = blockIdx.x * 256 + threadIdx.x;
  const int stride = gridDim.x * 256;
  for (; i < E; i += stride) {
    const int d = dst[i];
    const int p = atomicAdd(&cur[d], 1);
    srcs[p] = src[i];
    ws[p] = w[i];
  }
}

// ---------- GCN: out[row] = b + sum_{e in row} w[e] * sup[srcs[e]] ----------
__global__ __launch_bounds__(256) void gcn_gather(const int* __restrict__ rp,
                                                  const int* __restrict__ srcs,
                                                  const float* __restrict__ w,
                                                  const float* __restrict__ sup,
                                                  const float* __restrict__ b,
                                                  float* __restrict__ out, int N) {
  const int wid = (blockIdx.x * 256 + threadIdx.x) >> 6;
  const int lane = threadIdx.x & 63;
  if (wid >= N) return;
  const int beg = rp[wid], end = rp[wid + 1];
  const int slot = lane >> 4, c4 = (lane & 15) * 4;
  float4 acc = {0.f, 0.f, 0.f, 0.f};
  for (int j = beg + slot; j < end; j += 4) {
    const int s = srcs[j];
    const float wv = w[j];
    const float4 v = *(const float4*)&sup[(size_t)s * 64 + c4];
    acc.x += wv * v.x; acc.y += wv * v.y; acc.z += wv * v.z; acc.w += wv * v.w;
  }
#pragma unroll
  for (int m = 16; m <= 32; m <<= 1) {
    acc.x += __shfl_xor(acc.x, m);
    acc.y += __shfl_xor(acc.y, m);
    acc.z += __shfl_xor(acc.z, m);
    acc.w += __shfl_xor(acc.w, m);
  }
  if (lane < 16) {
    const float4 bv = *(const float4*)&b[c4];
    acc.x += bv.x; acc.y += bv.y; acc.z += bv.z; acc.w += bv.w;
    *(float4*)&out[(size_t)wid * 64 + c4] = acc;
  }
}

// ---------- fused GAT: per dst row: max pass, then exp+den+weighted gather ----------
__global__ __launch_bounds__(256) void gat_fused(const int* __restrict__ rp,
                                                 const int* __restrict__ srcs,
                                                 const float* __restrict__ sdst,
                                                 const float* __restrict__ ssrc,
                                                 const float* __restrict__ hs,
                                                 float* __restrict__ out, int N) {
  const int wid = (blockIdx.x * 256 + threadIdx.x) >> 6;
  const int lane = threadIdx.x & 63;
  if (wid >= N) return;
  const int beg = rp[wid], end = rp[wid + 1];
  const int deg = end - beg;
  const float sd = sdst[wid];
  float m = -3.4e38f;
  for (int k = lane; k < deg; k += 64) {
    float v = sd + ssrc[srcs[beg + k]];
    v = (v >= 0.f) ? v : 0.2f * v;
    m = fmaxf(m, v);
  }
#pragma unroll
  for (int off = 1; off < 64; off <<= 1) m = fmaxf(m, __shfl_xor(m, off));
  const int slot = lane >> 4, c4 = (lane & 15) * 4;
  float4 acc = {0.f, 0.f, 0.f, 0.f};
  float den = 0.f;
  for (int j = beg + slot; j < end; j += 4) {
    const int s = srcs[j];
    float v = sd + ssrc[s];
    v = (v >= 0.f) ? v : 0.2f * v;
    const float ex = expf(v - m);
    const float4 hv = *(const float4*)&hs[(size_t)s * 64 + c4];
    acc.x += ex * hv.x; acc.y += ex * hv.y; acc.z += ex * hv.z; acc.w += ex * hv.w;
    den += ex;  // same value across the 16 lanes of this slot
  }
#pragma unroll
  for (int mm = 16; mm <= 32; mm <<= 1) {
    acc.x += __shfl_xor(acc.x, mm);
    acc.y += __shfl_xor(acc.y, mm);
    acc.z += __shfl_xor(acc.z, mm);
    acc.w += __shfl_xor(acc.w, mm);
    den   += __shfl_xor(den, mm);
  }
  if (lane < 16) {
    const float inv = 1.f / (den + 1e-16f);
    acc.x *= inv; acc.y *= inv; acc.z *= inv; acc.w *= inv;
    *(float4*)&out[(size_t)wid * 64 + c4] = acc;
  }
}

extern "C" void kernel_launch(void* const* d_in, const int* in_sizes, int n_in,
                              void* d_out, int out_size, void* d_ws, size_t ws_size,
                              hipStream_t stream) {
  const float* ufea   = (const float*)d_in[0];
  const float* vfea   = (const float*)d_in[1];
  const int*   edge_user = (const int*)d_in[2];
  const int*   edge_item = (const int*)d_in[3];
  const float* uv_w   = (const float*)d_in[4];
  const float* vu_w   = (const float*)d_in[5];
  const float* W_gc1  = (const float*)d_in[6];
  const float* b_gc1  = (const float*)d_in[7];
  const float* W_gc2  = (const float*)d_in[8];
  const float* b_gc2  = (const float*)d_in[9];
  const float* W_gat3 = (const float*)d_in[10];
  const float* a_gat3 = (const float*)d_in[11];
  const float* W_gat4 = (const float*)d_in[12];
  const float* a_gat4 = (const float*)d_in[13];
  const float* W_user = (const float*)d_in[14];
  const float* b_user = (const float*)d_in[15];
  const float* W_item = (const float*)d_in[16];
  const float* b_item = (const float*)d_in[17];

  const int NU = in_sizes[0] / 64;
  const int NI = in_sizes[1] / 64;
  const int E  = in_sizes[2];

  float* ws = (float*)d_ws;
  size_t o = 0;
  auto pad4 = [](size_t x) { return (x + 3) & ~(size_t)3; };  // keep 16B alignment
  float* P0 = ws + o; o += (size_t)NU * 64;   // support1 -> hs4
  float* P1 = ws + o; o += (size_t)NI * 64;   // support2 -> hs3
  float* P2 = ws + o; o += (size_t)NI * 64;   // user_ho_i -> item_ho
  float* P3 = ws + o; o += (size_t)NU * 64;   // item_ho_u -> user_ho
  float* s_dst3 = ws + o; o += NU;
  float* s_src3 = ws + o; o += NI;
  float* s_dst4 = ws + o; o += NI;
  float* s_src4 = ws + o; o += NU;
  float* cvec = ws + o; o += 256;
  // CSR by item (dst = edge_item)
  int* cntI = (int*)(ws + o); o += NI;
  int* rpI  = (int*)(ws + o); o += pad4(NI + 1);
  int* curI = (int*)(ws + o); o += NI;
  int* srcU_byI = (int*)(ws + o); o += E;
  float* wVU_byI = ws + o; o += E;
  // CSR by user (dst = edge_user)
  int* cntU = (int*)(ws + o); o += NU;
  int* rpU  = (int*)(ws + o); o += pad4(NU + 1);
  int* curU = (int*)(ws + o); o += NU;
  int* srcI_byU = (int*)(ws + o); o += E;
  float* wUV_byU = ws + o; o += E;
  // scan block sums
  int* bsI = (int*)(ws + o); o += 1024;
  int* bsU = (int*)(ws + o); o += 1024;

  float* out_user = (float*)d_out;
  float* out_item = out_user + (size_t)NU * 64;

  const dim3 blk(256);
  const int gU = (NU + 63) / 64, gI = (NI + 63) / 64;   // 64-row dense blocks
  const int gE = (E + 255) / 256;
  const int gEs = min(gE, 2048);            // grid-stride kernels
  const int gwU = (NU + 3) / 4, gwI = (NI + 3) / 4;  // wave-per-row kernels
  const int gvU = (int)(((long)NU * 16 + 255) / 256);
  const int gvI = (int)(((long)NI * 16 + 255) / 256);
  const int nbI = (NI + 1023) / 1024, nbU = (NU + 1023) / 1024;  // scan blocks

  // ---- CSR build (both directions) ----
  hipMemsetAsync(cntI, 0, (size_t)NI * 4, stream);
  hipMemsetAsync(cntU, 0, (size_t)NU * 4, stream);
  hist_kernel<<<gEs, blk, 0, stream>>>(edge_item, cntI, E);
  hist_kernel<<<gEs, blk, 0, stream>>>(edge_user, cntU, E);
  scan_partial<<<nbI, blk, 0, stream>>>(cntI, NI, bsI);
  scan_sums<<<1, 1024, 0, stream>>>(bsI, nbI);
  scan_blocks<<<nbI, blk, 0, stream>>>(cntI, NI, E, bsI, rpI, curI);
  scan_partial<<<nbU, blk, 0, stream>>>(cntU, NU, bsU);
  scan_sums<<<1, 1024, 0, stream>>>(bsU, nbU);
  scan_blocks<<<nbU, blk, 0, stream>>>(cntU, NU, E, bsU, rpU, curU);
  reorder_kernel<<<gEs, blk, 0, stream>>>(edge_item, edge_user, vu_w, curI, srcU_byI, wVU_byI, E);
  reorder_kernel<<<gEs, blk, 0, stream>>>(edge_user, edge_item, uv_w, curU, srcI_byU, wUV_byU, E);

  // ---- GCN supports ----
  mm64<<<gU, blk, 0, stream>>>(ufea, W_gc1, P0, NU);
  mm64<<<gI, blk, 0, stream>>>(vfea, W_gc2, P1, NI);

  // ---- GCN gather-accumulate (atomic-free) ----
  gcn_gather<<<gwI, blk, 0, stream>>>(rpI, srcU_byI, wVU_byI, P0, b_gc1, P2, NI);  // user_ho_i
  gcn_gather<<<gwU, blk, 0, stream>>>(rpU, srcI_byU, wUV_byU, P1, b_gc2, P3, NU);  // item_ho_u

  // ---- GAT attention scalar projections: s = x @ (W @ a_half) ----
  make_cvecs<<<1, 256, 0, stream>>>(W_gat3, a_gat3, W_gat4, a_gat4, cvec);
  matvec64<<<gvU, blk, 0, stream>>>(ufea, cvec + 0,   s_dst3, NU);
  matvec64<<<gvI, blk, 0, stream>>>(P2,   cvec + 64,  s_src3, NI);
  matvec64<<<gvI, blk, 0, stream>>>(vfea, cvec + 128, s_dst4, NI);
  matvec64<<<gvU, blk, 0, stream>>>(P3,   cvec + 192, s_src4, NU);

  // ---- h_src for both GATs (reuse P1/P0) ----
  mm64<<<gI, blk, 0, stream>>>(P2, W_gat3, P1, NI);  // hs3
  mm64<<<gU, blk, 0, stream>>>(P3, W_gat4, P0, NU);  // hs4

  // ---- fused GAT (atomic-free, single pass kernel per direction) ----
  gat_fused<<<gwU, blk, 0, stream>>>(rpU, srcI_byU, s_dst3, s_src3, P1, P3, NU);  // user_ho
  gat_fused<<<gwI, blk, 0, stream>>>(rpI, srcU_byI, s_dst4, s_src4, P0, P2, NI);  // item_ho

  // ---- final linear + relu ----
  final_mm<<<gU, blk, 0, stream>>>(P3, ufea, W_user, b_user, out_user, NU);
  final_mm<<<gI, blk, 0, stream>>>(P2, vfea, W_item, b_item, out_item, NI);
}